// Round 8
// baseline (371.140 us; speedup 1.0000x reference)
//
#include <hip/hip_runtime.h>
#include <hip/hip_bf16.h>

// Problem: B=64, S=512, D=512.
// out[b] = (sum_{valid i} max_{valid j} sim[i,j] + sum_{valid j} max_{valid i} sim[i,j]) / (n1+n2)
// sim = normalize(e1) @ normalize(e2)^T per batch.
//
// Round-8 (fused structure from r7 + three fixes):
//   - distance-3 global prefetch, two staging reg sets: chunk k+3 issued in
//     iter k, consumed in iter k+2 (~2 iters ≈ 800cyc ≥ HBM miss latency).
//   - XCD-aware 2x2 region swizzle: the 4 blocks of a (2rt x 2ct) region get
//     linear ids differing by 8 -> same XCD under round-robin -> each A/B
//     strip fetched by 2 XCDs (was 4) and co-resident sharers hit/merge in L2.
//   - LDS write swizzle s(r) includes r>>4 so rows r and r+16 no longer
//     collide (r7: 4.2M conflict cycles).
//   sim_fused   : fp32 -> regs -> cvt_pk bf16 -> ds_write (XOR-swizzled,
//                 double-buffered), row sum-of-squares fused from the same
//                 fp32 regs; inv norms applied to accumulators in epilogue
//                 (max commutes with positive scaling); masked row/col max
//                 partials -> ws.
//   final_kernel: per-batch reduction over 4x4 partials -> out.
// ws: 1 MB (partial maxes only).

typedef __attribute__((ext_vector_type(8))) short bf16x8;   // 8 bf16 in 4 VGPRs
typedef __attribute__((ext_vector_type(4))) float f32x4;

#define NEGBIG (-1e9f)

__device__ __forceinline__ unsigned packbf2_hw(float lo, float hi) {
    __hip_bfloat162 h = __float22bfloat162_rn(float2{lo, hi});
    union { __hip_bfloat162 h; unsigned u; } c; c.h = h;
    return c.u;
}

// ---------------- kernel 1: fused cast+norm+GEMM+masked-max ----------------
// 1D grid 1024, swizzle-decoded to (b, rt, ct). 256 thr = 4 waves (2x2 of 64x64).
// Tile 128x128, BK=32, double-buffered bf16 LDS tiles written via ds_write_b128.
// LDS layout: row stride 32 ushorts, chunk c at slot c ^ s(row),
// s(r) = (r ^ (r>>2) ^ (r>>4)) & 3.
__global__ __launch_bounds__(256, 3)
void sim_fused(const float* __restrict__ e1, const float* __restrict__ e2,
               const int* __restrict__ m1g, const int* __restrict__ m2g,
               float* __restrict__ rowmax_p,   // [B][4][512]
               float* __restrict__ colmax_p)   // [B][4][512]
{
    // ---- XCD 2x2-region swizzle (8 XCDs, round-robin on linear id)
    const int id   = blockIdx.x;
    const int xcd  = id & 7;
    const int k2   = id >> 3;
    const int wi   = k2 & 3;            // which block within the 2x2 region
    const int rg   = k2 >> 2;           // region slot on this XCD (0..31)
    const int glob = rg * 8 + xcd;      // global region id (0..255)
    const int b    = glob >> 2;
    const int rq   = glob & 3;          // region (i,j): i=rq>>1, j=rq&1
    const int rt   = ((rq >> 1) << 1) | (wi & 1);
    const int ct   = ((rq & 1) << 1) | (wi >> 1);

    const int tid = threadIdx.x;
    const int lane = tid & 63;
    const int w    = tid >> 6;
    const int wm   = w >> 1;
    const int wn   = w & 1;
    const int q    = lane >> 4;
    const int ln   = lane & 15;
    const int nb   = ct * 128;                  // global col base

    __shared__ __align__(16) ushort sA[2][128 * 32];   // 2 x 8 KB
    __shared__ __align__(16) ushort sB[2][128 * 32];   // 2 x 8 KB
    __shared__ float spr[2][128];
    __shared__ float spc[2][128];
    __shared__ int   sm1[128], sm2[128];
    __shared__ float sinv1[128], sinv2[128];

    if (tid < 128) sm1[tid] = m1g[b * 512 + rt * 128 + tid];
    else           sm2[tid - 128] = m2g[b * 512 + nb + (tid - 128)];

    // ---- staging mapping: thread (r = tid>>1, h = tid&1) covers row r,
    // k-local [h*16, h*16+16) each iter, for both A and B tiles.
    const int r = tid >> 1;
    const int h = tid & 1;
    const int s = (r ^ (r >> 2) ^ (r >> 4)) & 3;
    const float* gA = e1 + ((size_t)(b * 512 + rt * 128 + r)) * 512 + h * 16;
    const float* gB = e2 + ((size_t)(b * 512 + nb + r)) * 512 + h * 16;
    // chunk c = 2h, 2h+1 -> slot c ^ s (ushort offsets)
    const int wo0 = r * 32 + (((2 * h)     ^ s) << 3);
    const int wo1 = r * 32 + (((2 * h + 1) ^ s) << 3);

    // ---- fragment read offsets: slot q ^ s(frag_row), frag_row = base+ln
    int aoff[4], boff[4];
    #pragma unroll
    for (int mt = 0; mt < 4; ++mt) {
        int fr = wm * 64 + mt * 16 + ln;
        int fs = (fr ^ (fr >> 2) ^ (fr >> 4)) & 3;
        aoff[mt] = fr * 32 + ((q ^ fs) << 3);
    }
    #pragma unroll
    for (int nt = 0; nt < 4; ++nt) {
        int fr = wn * 64 + nt * 16 + ln;
        int fs = (fr ^ (fr >> 2) ^ (fr >> 4)) & 3;
        boff[nt] = fr * 32 + ((q ^ fs) << 3);
    }

    float ssA = 0.f, ssB = 0.f;
    float4 ra[2][4], rb[2][4];           // TWO staging sets (distance-3 prefetch)

    auto LOADK = [&](int st, int kf) {   // kf = float offset of chunk
        const float4* pa = reinterpret_cast<const float4*>(gA + kf);
        const float4* pb = reinterpret_cast<const float4*>(gB + kf);
        ra[st][0] = pa[0]; ra[st][1] = pa[1]; ra[st][2] = pa[2]; ra[st][3] = pa[3];
        rb[st][0] = pb[0]; rb[st][1] = pb[1]; rb[st][2] = pb[2]; rb[st][3] = pb[3];
    };
    auto CVTWRITE = [&](int p, int st) {
        #pragma unroll
        for (int i = 0; i < 4; ++i) {
            ssA += ra[st][i].x * ra[st][i].x + ra[st][i].y * ra[st][i].y
                 + ra[st][i].z * ra[st][i].z + ra[st][i].w * ra[st][i].w;
            ssB += rb[st][i].x * rb[st][i].x + rb[st][i].y * rb[st][i].y
                 + rb[st][i].z * rb[st][i].z + rb[st][i].w * rb[st][i].w;
        }
        uint4 u;
        u.x = packbf2_hw(ra[st][0].x, ra[st][0].y); u.y = packbf2_hw(ra[st][0].z, ra[st][0].w);
        u.z = packbf2_hw(ra[st][1].x, ra[st][1].y); u.w = packbf2_hw(ra[st][1].z, ra[st][1].w);
        *reinterpret_cast<uint4*>(&sA[p][wo0]) = u;
        u.x = packbf2_hw(ra[st][2].x, ra[st][2].y); u.y = packbf2_hw(ra[st][2].z, ra[st][2].w);
        u.z = packbf2_hw(ra[st][3].x, ra[st][3].y); u.w = packbf2_hw(ra[st][3].z, ra[st][3].w);
        *reinterpret_cast<uint4*>(&sA[p][wo1]) = u;
        u.x = packbf2_hw(rb[st][0].x, rb[st][0].y); u.y = packbf2_hw(rb[st][0].z, rb[st][0].w);
        u.z = packbf2_hw(rb[st][1].x, rb[st][1].y); u.w = packbf2_hw(rb[st][1].z, rb[st][1].w);
        *reinterpret_cast<uint4*>(&sB[p][wo0]) = u;
        u.x = packbf2_hw(rb[st][2].x, rb[st][2].y); u.y = packbf2_hw(rb[st][2].z, rb[st][2].w);
        u.z = packbf2_hw(rb[st][3].x, rb[st][3].y); u.w = packbf2_hw(rb[st][3].z, rb[st][3].w);
        *reinterpret_cast<uint4*>(&sB[p][wo1]) = u;
    };

    f32x4 acc[4][4];
    #pragma unroll
    for (int i = 0; i < 4; ++i)
        #pragma unroll
        for (int j = 0; j < 4; ++j)
            acc[i][j] = (f32x4){0.f, 0.f, 0.f, 0.f};

    // prologue: chunk0 -> buf0 via set1 (immediately consumed);
    // then prefetch chunk1 -> set0, chunk2 -> set1.
    LOADK(1, 0);
    CVTWRITE(0, 1);
    LOADK(0, 32);
    LOADK(1, 64);
    __syncthreads();

    // Steady state (iter k, p = k&1, st = k&1):
    //   consume chunk k+1 (set st, issued at iter k-2), issue chunk k+3 into
    //   the freed set. Loads get ~2 iters to land.
    #pragma unroll 2
    for (int k = 0; k < 16; ++k) {
        const int p  = k & 1;
        const int st = k & 1;
        bf16x8 af[4], bfr[4];
        #pragma unroll
        for (int mt = 0; mt < 4; ++mt)
            af[mt] = *reinterpret_cast<const bf16x8*>(&sA[p][aoff[mt]]);
        #pragma unroll
        for (int nt = 0; nt < 4; ++nt)
            bfr[nt] = *reinterpret_cast<const bf16x8*>(&sB[p][boff[nt]]);
        if (k < 15) CVTWRITE(p ^ 1, st);      // chunk k+1 -> other buffer
        if (k < 13) LOADK(st, (k + 3) * 32);  // chunk k+3 -> freed set
        #pragma unroll
        for (int mt = 0; mt < 4; ++mt)
            #pragma unroll
            for (int nt = 0; nt < 4; ++nt)
                acc[mt][nt] = __builtin_amdgcn_mfma_f32_16x16x32_bf16(
                    af[mt], bfr[nt], acc[mt][nt], 0, 0, 0);
        __syncthreads();   // tile p reads done by all waves; tile p^1 visible
    }

    // ---- finish norms: thread pair (2r, 2r+1) holds half-row sums each
    ssA += __shfl_xor(ssA, 1);
    ssB += __shfl_xor(ssB, 1);
    if (h == 0) {
        sinv1[r] = 1.0f / fmaxf(sqrtf(ssA), 1e-8f);
        sinv2[r] = 1.0f / fmaxf(sqrtf(ssB), 1e-8f);
    }
    __syncthreads();

    // ---- scale: sim = acc * inv_i * inv_j (C/D layout: col=ln, row=q*4+reg)
    float invj[4];
    f32x4 invi[4];
    #pragma unroll
    for (int nt = 0; nt < 4; ++nt)
        invj[nt] = sinv2[wn * 64 + nt * 16 + ln];
    #pragma unroll
    for (int mt = 0; mt < 4; ++mt)
        #pragma unroll
        for (int rg2 = 0; rg2 < 4; ++rg2)
            invi[mt][rg2] = sinv1[wm * 64 + mt * 16 + q * 4 + rg2];
    #pragma unroll
    for (int mt = 0; mt < 4; ++mt)
        #pragma unroll
        for (int nt = 0; nt < 4; ++nt)
            acc[mt][nt] = acc[mt][nt] * (invi[mt] * invj[nt]);

    // ---- masked row maxes (over this block's 128 cols)
    #pragma unroll
    for (int mt = 0; mt < 4; ++mt) {
        #pragma unroll
        for (int rg2 = 0; rg2 < 4; ++rg2) {
            float rm = NEGBIG;
            #pragma unroll
            for (int nt = 0; nt < 4; ++nt) {
                float v = sm2[wn * 64 + nt * 16 + ln] ? acc[mt][nt][rg2] : NEGBIG;
                rm = fmaxf(rm, v);
            }
            rm = fmaxf(rm, __shfl_xor(rm, 1));
            rm = fmaxf(rm, __shfl_xor(rm, 2));
            rm = fmaxf(rm, __shfl_xor(rm, 4));
            rm = fmaxf(rm, __shfl_xor(rm, 8));
            if (ln == 0) spr[wn][wm * 64 + mt * 16 + q * 4 + rg2] = rm;
        }
    }
    // ---- masked col maxes (over this block's 128 rows)
    #pragma unroll
    for (int nt = 0; nt < 4; ++nt) {
        float cm = NEGBIG;
        #pragma unroll
        for (int mt = 0; mt < 4; ++mt)
            #pragma unroll
            for (int rg2 = 0; rg2 < 4; ++rg2) {
                float v = sm1[wm * 64 + mt * 16 + q * 4 + rg2] ? acc[mt][nt][rg2] : NEGBIG;
                cm = fmaxf(cm, v);
            }
        cm = fmaxf(cm, __shfl_xor(cm, 16));
        cm = fmaxf(cm, __shfl_xor(cm, 32));
        if (lane < 16) spc[wm][wn * 64 + nt * 16 + ln] = cm;
    }
    __syncthreads();
    if (tid < 128) {
        rowmax_p[((size_t)b * 4 + ct) * 512 + rt * 128 + tid] =
            fmaxf(spr[0][tid], spr[1][tid]);
        colmax_p[((size_t)b * 4 + rt) * 512 + nb + tid] =
            fmaxf(spc[0][tid], spc[1][tid]);
    }
}

// ---------------- kernel 2: per-batch final reduction ----------------
__global__ __launch_bounds__(256)
void final_kernel(const int* __restrict__ m1g, const int* __restrict__ m2g,
                  const float* __restrict__ rowmax_p, const float* __restrict__ colmax_p,
                  float* __restrict__ out)
{
    const int b = blockIdx.x;
    const int tid = threadIdx.x;
    const int lane = tid & 63;
    const int w = tid >> 6;

    float sum = 0.f;
    float nn  = 0.f;
    for (int j = tid; j < 512; j += 256) {
        int mm1 = m1g[b * 512 + j];
        int mm2 = m2g[b * 512 + j];
        nn += (float)(mm1 + mm2);
        const float* rp = rowmax_p + (size_t)b * 2048 + j;
        float rm = fmaxf(fmaxf(rp[0], rp[512]), fmaxf(rp[1024], rp[1536]));
        if (mm1) sum += rm;
        const float* cp = colmax_p + (size_t)b * 2048 + j;
        float cm = fmaxf(fmaxf(cp[0], cp[512]), fmaxf(cp[1024], cp[1536]));
        if (mm2) sum += cm;
    }
    #pragma unroll
    for (int m = 32; m; m >>= 1) {
        sum += __shfl_xor(sum, m);
        nn  += __shfl_xor(nn, m);
    }
    __shared__ float ssum[4], snn[4];
    if (lane == 0) { ssum[w] = sum; snn[w] = nn; }
    __syncthreads();
    if (tid == 0) {
        float S = ssum[0] + ssum[1] + ssum[2] + ssum[3];
        float N = snn[0] + snn[1] + snn[2] + snn[3];
        out[b] = S / N;
    }
}

extern "C" void kernel_launch(void* const* d_in, const int* in_sizes, int n_in,
                              void* d_out, int out_size, void* d_ws, size_t ws_size,
                              hipStream_t stream) {
    const float* e1 = (const float*)d_in[0];
    const float* e2 = (const float*)d_in[1];
    const int*   m1 = (const int*)d_in[2];
    const int*   m2 = (const int*)d_in[3];
    float* out = (float*)d_out;

    float* ws = (float*)d_ws;             // 1 MB
    float* rowmax_p = ws;                 // 64*4*512
    float* colmax_p = ws + 131072;        // 64*4*512

    sim_fused<<<1024, 256, 0, stream>>>(e1, e2, m1, m2, rowmax_p, colmax_p);
    final_kernel<<<64, 256, 0, stream>>>(m1, m2, rowmax_p, colmax_p, out);
}

// Round 9
// 184.400 us; speedup vs baseline: 2.0127x; 2.0127x over previous
//
#include <hip/hip_runtime.h>
#include <hip/hip_bf16.h>

// Problem: B=64, S=512, D=512.
// out[b] = (sum_{valid i} max_{valid j} sim[i,j] + sum_{valid j} max_{valid i} sim[i,j]) / (n1+n2)
// sim = normalize(e1) @ normalize(e2)^T per batch.
//
// Round-9 = r7's proven fused structure (78us; r8's distance-3 prefetch
// SPILLED to scratch: VGPR 84 + 459MB scratch writes -> 274us. Reverted.)
// plus the two orthogonal r8 fixes, minus the fatal one:
//   - XCD 2x2-region swizzle: 4 blocks sharing A/B strips -> same XCD L2.
//   - LDS write swizzle s(r) = (r ^ (r>>2) ^ (r>>4)) & 3: rows r, r+16 no
//     longer collide (r7: 4.2M conflict cycles).
//   - LOADK issued first in the iter body (max time before barrier drain).
//   sim_fused   : fp32 -> regs (ONE staging set, distance-1) -> cvt_pk bf16
//                 -> ds_write_b128 (XOR-swizzled, double-buffered tiles);
//                 row sum-of-squares fused from the same fp32 regs; inv norms
//                 applied to accumulators in epilogue (max commutes with
//                 positive scaling); masked row/col max partials -> ws.
//   final_kernel: per-batch reduction over 4x4 partials -> out.
// ws: 1 MB (partial maxes only).

typedef __attribute__((ext_vector_type(8))) short bf16x8;   // 8 bf16 in 4 VGPRs
typedef __attribute__((ext_vector_type(4))) float f32x4;

#define NEGBIG (-1e9f)

__device__ __forceinline__ unsigned packbf2_hw(float lo, float hi) {
    __hip_bfloat162 h = __float22bfloat162_rn(float2{lo, hi});
    union { __hip_bfloat162 h; unsigned u; } c; c.h = h;
    return c.u;
}

// ---------------- kernel 1: fused cast+norm+GEMM+masked-max ----------------
// 1D grid 1024, swizzle-decoded to (b, rt, ct). 256 thr = 4 waves (2x2 of 64x64).
// Tile 128x128, BK=32, double-buffered bf16 LDS tiles written via ds_write_b128.
// LDS layout: row stride 32 ushorts, chunk c at slot c ^ s(row).
__global__ __launch_bounds__(256)
void sim_fused(const float* __restrict__ e1, const float* __restrict__ e2,
               const int* __restrict__ m1g, const int* __restrict__ m2g,
               float* __restrict__ rowmax_p,   // [B][4][512]
               float* __restrict__ colmax_p)   // [B][4][512]
{
    // ---- XCD 2x2-region swizzle (8 XCDs, round-robin on linear id)
    const int id   = blockIdx.x;
    const int xcd  = id & 7;
    const int k2   = id >> 3;
    const int wi   = k2 & 3;            // which block within the 2x2 region
    const int rg   = k2 >> 2;           // region slot on this XCD (0..31)
    const int glob = rg * 8 + xcd;      // global region id (0..255)
    const int b    = glob >> 2;
    const int rq   = glob & 3;          // region (i,j): i=rq>>1, j=rq&1
    const int rt   = ((rq >> 1) << 1) | (wi & 1);
    const int ct   = ((rq & 1) << 1) | (wi >> 1);

    const int tid = threadIdx.x;
    const int lane = tid & 63;
    const int w    = tid >> 6;
    const int wm   = w >> 1;
    const int wn   = w & 1;
    const int q    = lane >> 4;
    const int ln   = lane & 15;
    const int nb   = ct * 128;                  // global col base

    __shared__ __align__(16) ushort sA[2][128 * 32];   // 2 x 8 KB
    __shared__ __align__(16) ushort sB[2][128 * 32];   // 2 x 8 KB
    __shared__ float spr[2][128];
    __shared__ float spc[2][128];
    __shared__ int   sm1[128], sm2[128];
    __shared__ float sinv1[128], sinv2[128];

    if (tid < 128) sm1[tid] = m1g[b * 512 + rt * 128 + tid];
    else           sm2[tid - 128] = m2g[b * 512 + nb + (tid - 128)];

    // ---- staging mapping: thread (r = tid>>1, h = tid&1) covers row r,
    // k-local [h*16, h*16+16) each iter, for both A and B tiles.
    const int r = tid >> 1;
    const int h = tid & 1;
    const int s = (r ^ (r >> 2) ^ (r >> 4)) & 3;
    const float* gA = e1 + ((size_t)(b * 512 + rt * 128 + r)) * 512 + h * 16;
    const float* gB = e2 + ((size_t)(b * 512 + nb + r)) * 512 + h * 16;
    // chunk c = 2h, 2h+1 -> slot c ^ s (ushort offsets)
    const int wo0 = r * 32 + (((2 * h)     ^ s) << 3);
    const int wo1 = r * 32 + (((2 * h + 1) ^ s) << 3);

    // ---- fragment read offsets: slot q ^ s(frag_row), frag_row = base+ln
    int aoff[4], boff[4];
    #pragma unroll
    for (int mt = 0; mt < 4; ++mt) {
        int fr = wm * 64 + mt * 16 + ln;
        int fs = (fr ^ (fr >> 2) ^ (fr >> 4)) & 3;
        aoff[mt] = fr * 32 + ((q ^ fs) << 3);
    }
    #pragma unroll
    for (int nt = 0; nt < 4; ++nt) {
        int fr = wn * 64 + nt * 16 + ln;
        int fs = (fr ^ (fr >> 2) ^ (fr >> 4)) & 3;
        boff[nt] = fr * 32 + ((q ^ fs) << 3);
    }

    float ssA = 0.f, ssB = 0.f;
    float4 ra[4], rb[4];                 // ONE staging set (r7-proven, no spill)

    auto LOADK = [&](int kf) {           // kf = float offset of chunk
        const float4* pa = reinterpret_cast<const float4*>(gA + kf);
        const float4* pb = reinterpret_cast<const float4*>(gB + kf);
        ra[0] = pa[0]; ra[1] = pa[1]; ra[2] = pa[2]; ra[3] = pa[3];
        rb[0] = pb[0]; rb[1] = pb[1]; rb[2] = pb[2]; rb[3] = pb[3];
    };
    auto CVTWRITE = [&](int p) {
        #pragma unroll
        for (int i = 0; i < 4; ++i) {
            ssA += ra[i].x * ra[i].x + ra[i].y * ra[i].y
                 + ra[i].z * ra[i].z + ra[i].w * ra[i].w;
            ssB += rb[i].x * rb[i].x + rb[i].y * rb[i].y
                 + rb[i].z * rb[i].z + rb[i].w * rb[i].w;
        }
        uint4 u;
        u.x = packbf2_hw(ra[0].x, ra[0].y); u.y = packbf2_hw(ra[0].z, ra[0].w);
        u.z = packbf2_hw(ra[1].x, ra[1].y); u.w = packbf2_hw(ra[1].z, ra[1].w);
        *reinterpret_cast<uint4*>(&sA[p][wo0]) = u;
        u.x = packbf2_hw(ra[2].x, ra[2].y); u.y = packbf2_hw(ra[2].z, ra[2].w);
        u.z = packbf2_hw(ra[3].x, ra[3].y); u.w = packbf2_hw(ra[3].z, ra[3].w);
        *reinterpret_cast<uint4*>(&sA[p][wo1]) = u;
        u.x = packbf2_hw(rb[0].x, rb[0].y); u.y = packbf2_hw(rb[0].z, rb[0].w);
        u.z = packbf2_hw(rb[1].x, rb[1].y); u.w = packbf2_hw(rb[1].z, rb[1].w);
        *reinterpret_cast<uint4*>(&sB[p][wo0]) = u;
        u.x = packbf2_hw(rb[2].x, rb[2].y); u.y = packbf2_hw(rb[2].z, rb[2].w);
        u.z = packbf2_hw(rb[3].x, rb[3].y); u.w = packbf2_hw(rb[3].z, rb[3].w);
        *reinterpret_cast<uint4*>(&sB[p][wo1]) = u;
    };

    f32x4 acc[4][4];
    #pragma unroll
    for (int i = 0; i < 4; ++i)
        #pragma unroll
        for (int j = 0; j < 4; ++j)
            acc[i][j] = (f32x4){0.f, 0.f, 0.f, 0.f};

    // prologue: chunk 0 -> buf0; issue loads for chunk 1
    LOADK(0);
    CVTWRITE(0);
    LOADK(32);
    __syncthreads();

    #pragma unroll 2
    for (int k = 0; k < 16; ++k) {
        const int p = k & 1;
        bf16x8 af[4], bfr[4];
        #pragma unroll
        for (int mt = 0; mt < 4; ++mt)
            af[mt] = *reinterpret_cast<const bf16x8*>(&sA[p][aoff[mt]]);
        #pragma unroll
        for (int nt = 0; nt < 4; ++nt)
            bfr[nt] = *reinterpret_cast<const bf16x8*>(&sB[p][boff[nt]]);
        if (k < 15) CVTWRITE(p ^ 1);          // consumes regs (chunk k+1)
        if (k < 14) LOADK((k + 2) * 32);      // refill regs (chunk k+2)
        #pragma unroll
        for (int mt = 0; mt < 4; ++mt)
            #pragma unroll
            for (int nt = 0; nt < 4; ++nt)
                acc[mt][nt] = __builtin_amdgcn_mfma_f32_16x16x32_bf16(
                    af[mt], bfr[nt], acc[mt][nt], 0, 0, 0);
        __syncthreads();   // tile p reads done by all waves; tile p^1 visible
    }

    // ---- finish norms: thread pair (2r, 2r+1) holds half-row sums each
    ssA += __shfl_xor(ssA, 1);
    ssB += __shfl_xor(ssB, 1);
    if (h == 0) {
        sinv1[r] = 1.0f / fmaxf(sqrtf(ssA), 1e-8f);
        sinv2[r] = 1.0f / fmaxf(sqrtf(ssB), 1e-8f);
    }
    __syncthreads();

    // ---- scale: sim = acc * inv_i * inv_j (C/D layout: col=ln, row=q*4+reg)
    float invj[4];
    f32x4 invi[4];
    #pragma unroll
    for (int nt = 0; nt < 4; ++nt)
        invj[nt] = sinv2[wn * 64 + nt * 16 + ln];
    #pragma unroll
    for (int mt = 0; mt < 4; ++mt)
        #pragma unroll
        for (int rg2 = 0; rg2 < 4; ++rg2)
            invi[mt][rg2] = sinv1[wm * 64 + mt * 16 + q * 4 + rg2];
    #pragma unroll
    for (int mt = 0; mt < 4; ++mt)
        #pragma unroll
        for (int nt = 0; nt < 4; ++nt)
            acc[mt][nt] = acc[mt][nt] * (invi[mt] * invj[nt]);

    // ---- masked row maxes (over this block's 128 cols)
    #pragma unroll
    for (int mt = 0; mt < 4; ++mt) {
        #pragma unroll
        for (int rg2 = 0; rg2 < 4; ++rg2) {
            float rm = NEGBIG;
            #pragma unroll
            for (int nt = 0; nt < 4; ++nt) {
                float v = sm2[wn * 64 + nt * 16 + ln] ? acc[mt][nt][rg2] : NEGBIG;
                rm = fmaxf(rm, v);
            }
            rm = fmaxf(rm, __shfl_xor(rm, 1));
            rm = fmaxf(rm, __shfl_xor(rm, 2));
            rm = fmaxf(rm, __shfl_xor(rm, 4));
            rm = fmaxf(rm, __shfl_xor(rm, 8));
            if (ln == 0) spr[wn][wm * 64 + mt * 16 + q * 4 + rg2] = rm;
        }
    }
    // ---- masked col maxes (over this block's 128 rows)
    #pragma unroll
    for (int nt = 0; nt < 4; ++nt) {
        float cm = NEGBIG;
        #pragma unroll
        for (int mt = 0; mt < 4; ++mt)
            #pragma unroll
            for (int rg2 = 0; rg2 < 4; ++rg2) {
                float v = sm1[wm * 64 + mt * 16 + q * 4 + rg2] ? acc[mt][nt][rg2] : NEGBIG;
                cm = fmaxf(cm, v);
            }
        cm = fmaxf(cm, __shfl_xor(cm, 16));
        cm = fmaxf(cm, __shfl_xor(cm, 32));
        if (lane < 16) spc[wm][wn * 64 + nt * 16 + ln] = cm;
    }
    __syncthreads();
    if (tid < 128) {
        rowmax_p[((size_t)b * 4 + ct) * 512 + rt * 128 + tid] =
            fmaxf(spr[0][tid], spr[1][tid]);
        colmax_p[((size_t)b * 4 + rt) * 512 + nb + tid] =
            fmaxf(spc[0][tid], spc[1][tid]);
    }
}

// ---------------- kernel 2: per-batch final reduction ----------------
__global__ __launch_bounds__(256)
void final_kernel(const int* __restrict__ m1g, const int* __restrict__ m2g,
                  const float* __restrict__ rowmax_p, const float* __restrict__ colmax_p,
                  float* __restrict__ out)
{
    const int b = blockIdx.x;
    const int tid = threadIdx.x;
    const int lane = tid & 63;
    const int w = tid >> 6;

    float sum = 0.f;
    float nn  = 0.f;
    for (int j = tid; j < 512; j += 256) {
        int mm1 = m1g[b * 512 + j];
        int mm2 = m2g[b * 512 + j];
        nn += (float)(mm1 + mm2);
        const float* rp = rowmax_p + (size_t)b * 2048 + j;
        float rm = fmaxf(fmaxf(rp[0], rp[512]), fmaxf(rp[1024], rp[1536]));
        if (mm1) sum += rm;
        const float* cp = colmax_p + (size_t)b * 2048 + j;
        float cm = fmaxf(fmaxf(cp[0], cp[512]), fmaxf(cp[1024], cp[1536]));
        if (mm2) sum += cm;
    }
    #pragma unroll
    for (int m = 32; m; m >>= 1) {
        sum += __shfl_xor(sum, m);
        nn  += __shfl_xor(nn, m);
    }
    __shared__ float ssum[4], snn[4];
    if (lane == 0) { ssum[w] = sum; snn[w] = nn; }
    __syncthreads();
    if (tid == 0) {
        float S = ssum[0] + ssum[1] + ssum[2] + ssum[3];
        float N = snn[0] + snn[1] + snn[2] + snn[3];
        out[b] = S / N;
    }
}

extern "C" void kernel_launch(void* const* d_in, const int* in_sizes, int n_in,
                              void* d_out, int out_size, void* d_ws, size_t ws_size,
                              hipStream_t stream) {
    const float* e1 = (const float*)d_in[0];
    const float* e2 = (const float*)d_in[1];
    const int*   m1 = (const int*)d_in[2];
    const int*   m2 = (const int*)d_in[3];
    float* out = (float*)d_out;

    float* ws = (float*)d_ws;             // 1 MB
    float* rowmax_p = ws;                 // 64*4*512
    float* colmax_p = ws + 131072;        // 64*4*512

    sim_fused<<<1024, 256, 0, stream>>>(e1, e2, m1, m2, rowmax_p, colmax_p);
    final_kernel<<<64, 256, 0, stream>>>(m1, m2, rowmax_p, colmax_p, out);
}